// Round 1
// baseline (1424.967 us; speedup 1.0000x reference)
//
#include <hip/hip_runtime.h>

#define NDIM 64
#define EDIM 16
#define SCAN_BS 256
#define SCAN_TILE 2048   // SCAN_BS * 8

// ---------------- CSR build ----------------

__global__ __launch_bounds__(256) void hist_kernel(const int* __restrict__ edge_index,
                                                   int* __restrict__ deg, int E) {
    int e = blockIdx.x * blockDim.x + threadIdx.x;
    if (e < E) atomicAdd(&deg[edge_index[E + e]], 1);   // dst row
}

__global__ __launch_bounds__(SCAN_BS) void scan_tile_kernel(const int* __restrict__ deg,
                                                            int* __restrict__ excl,
                                                            int* __restrict__ tsum, int n) {
    __shared__ int sdata[SCAN_BS];
    int base = blockIdx.x * SCAN_TILE + threadIdx.x * 8;
    int v[8]; int s = 0;
#pragma unroll
    for (int j = 0; j < 8; ++j) { int idx = base + j; int val = (idx < n) ? deg[idx] : 0; v[j] = val; s += val; }
    sdata[threadIdx.x] = s;
    __syncthreads();
    for (int off = 1; off < SCAN_BS; off <<= 1) {
        int t = (threadIdx.x >= (unsigned)off) ? sdata[threadIdx.x - off] : 0;
        __syncthreads();
        sdata[threadIdx.x] += t;
        __syncthreads();
    }
    int incl = sdata[threadIdx.x];
    if (threadIdx.x == SCAN_BS - 1) tsum[blockIdx.x] = incl;
    int run = incl - s;  // exclusive prefix for this thread's chunk
#pragma unroll
    for (int j = 0; j < 8; ++j) { int idx = base + j; if (idx < n) excl[idx] = run; run += v[j]; }
}

__global__ void scan_sums_kernel(int* tsum, int ntiles) {
    if (threadIdx.x == 0 && blockIdx.x == 0) {
        int run = 0;
        for (int i = 0; i < ntiles; ++i) { int t = tsum[i]; tsum[i] = run; run += t; }
    }
}

__global__ __launch_bounds__(256) void scan_add_kernel(int* __restrict__ rowptr,
                                                       const int* __restrict__ tsum,
                                                       int* __restrict__ fillc, int n, int E) {
    int i = blockIdx.x * blockDim.x + threadIdx.x;
    if (i < n) {
        int v = rowptr[i] + tsum[i / SCAN_TILE];
        rowptr[i] = v;
        fillc[i] = v;
    }
    if (i == 0) rowptr[n] = E;
}

__global__ __launch_bounds__(256) void fill_kernel(const int* __restrict__ edge_index,
                                                   int* __restrict__ fillc,
                                                   int* __restrict__ srcs,
                                                   int* __restrict__ eids, int E) {
    int e = blockIdx.x * blockDim.x + threadIdx.x;
    if (e < E) {
        int d = edge_index[E + e];
        int pos = atomicAdd(&fillc[d], 1);
        srcs[pos] = edge_index[e];   // src row
        eids[pos] = e;
    }
}

// ---------------- fused GINEConv layer ----------------
// One wave per node; lane = channel. Gather-style aggregation (no atomics),
// edge transform on the fly, MLP via __shfl broadcast, weights in LDS.

__global__ __launch_bounds__(256) void layer_kernel(
    const float* __restrict__ xin, float* __restrict__ xout,
    const int* __restrict__ rowptr, const int* __restrict__ srcs, const int* __restrict__ eids,
    const float* __restrict__ edge_attr,
    const float* __restrict__ lin_e, const float* __restrict__ W1, const float* __restrict__ b1,
    const float* __restrict__ W2, const float* __restrict__ b2, const float* __restrict__ eps,
    int layer, int n_nodes)
{
    __shared__ float s_le[EDIM * NDIM];
    __shared__ float s_W1[NDIM * NDIM];
    __shared__ float s_W2[NDIM * NDIM];
    __shared__ float s_b1[NDIM];
    __shared__ float s_b2[NDIM];
    const float* le = lin_e + (size_t)layer * EDIM * NDIM;
    const float* w1 = W1 + (size_t)layer * NDIM * NDIM;
    const float* w2 = W2 + (size_t)layer * NDIM * NDIM;
    for (int i = threadIdx.x; i < EDIM * NDIM; i += 256) s_le[i] = le[i];
    for (int i = threadIdx.x; i < NDIM * NDIM; i += 256) { s_W1[i] = w1[i]; s_W2[i] = w2[i]; }
    if (threadIdx.x < NDIM) {
        s_b1[threadIdx.x] = b1[layer * NDIM + threadIdx.x];
        s_b2[threadIdx.x] = b2[layer * NDIM + threadIdx.x];
    }
    __syncthreads();
    const float eps1 = 1.0f + eps[layer];
    const int lane = threadIdx.x & 63;
    int gw = (blockIdx.x * blockDim.x + threadIdx.x) >> 6;
    int nw = (gridDim.x * blockDim.x) >> 6;
    for (int node = gw; node < n_nodes; node += nw) {
        int p0 = rowptr[node], p1 = rowptr[node + 1];
        float aggr = 0.0f;
        for (int p = p0; p < p1; ++p) {
            int s = srcs[p];
            int e = eids[p];
            float xs = xin[(size_t)s * NDIM + lane];                 // coalesced 256B row
            const float4* ea = (const float4*)(edge_attr + (size_t)e * EDIM);
            float4 a0 = ea[0], a1 = ea[1], a2 = ea[2], a3 = ea[3];   // wave-broadcast
            float acc = xs;
            acc = fmaf(a0.x, s_le[ 0*NDIM+lane], acc); acc = fmaf(a0.y, s_le[ 1*NDIM+lane], acc);
            acc = fmaf(a0.z, s_le[ 2*NDIM+lane], acc); acc = fmaf(a0.w, s_le[ 3*NDIM+lane], acc);
            acc = fmaf(a1.x, s_le[ 4*NDIM+lane], acc); acc = fmaf(a1.y, s_le[ 5*NDIM+lane], acc);
            acc = fmaf(a1.z, s_le[ 6*NDIM+lane], acc); acc = fmaf(a1.w, s_le[ 7*NDIM+lane], acc);
            acc = fmaf(a2.x, s_le[ 8*NDIM+lane], acc); acc = fmaf(a2.y, s_le[ 9*NDIM+lane], acc);
            acc = fmaf(a2.z, s_le[10*NDIM+lane], acc); acc = fmaf(a2.w, s_le[11*NDIM+lane], acc);
            acc = fmaf(a3.x, s_le[12*NDIM+lane], acc); acc = fmaf(a3.y, s_le[13*NDIM+lane], acc);
            acc = fmaf(a3.z, s_le[14*NDIM+lane], acc); acc = fmaf(a3.w, s_le[15*NDIM+lane], acc);
            aggr += fmaxf(acc, 0.0f);
        }
        float h = fmaf(eps1, xin[(size_t)node * NDIM + lane], aggr);
        float o1 = s_b1[lane];
#pragma unroll 8
        for (int k = 0; k < NDIM; ++k) o1 = fmaf(__shfl(h, k), s_W1[k * NDIM + lane], o1);
        o1 = fmaxf(o1, 0.0f);
        float o2 = s_b2[lane];
#pragma unroll 8
        for (int k = 0; k < NDIM; ++k) o2 = fmaf(__shfl(o1, k), s_W2[k * NDIM + lane], o2);
        xout[(size_t)node * NDIM + lane] = fmaxf(o2, 0.0f);
    }
}

// ---------------- pooling + head ----------------

__global__ __launch_bounds__(256) void pool_kernel(const float* __restrict__ x,
                                                   const int* __restrict__ batch,
                                                   float* __restrict__ pooled,
                                                   float* __restrict__ cnt, int n_nodes) {
    const int lane = threadIdx.x & 63;
    int gw = (blockIdx.x * blockDim.x + threadIdx.x) >> 6;
    int nw = (gridDim.x * blockDim.x) >> 6;
    for (int node = gw; node < n_nodes; node += nw) {
        int g = batch[node];
        atomicAdd(&pooled[(size_t)g * NDIM + lane], x[(size_t)node * NDIM + lane]);
        if (lane == 0) atomicAdd(&cnt[g], 1.0f);
    }
}

__global__ __launch_bounds__(256) void head_kernel(const float* __restrict__ pooled,
                                                   const float* __restrict__ cnt,
                                                   const float* __restrict__ t_cond,
                                                   const float* __restrict__ hW1,
                                                   const float* __restrict__ hb1,
                                                   const float* __restrict__ hW2,
                                                   const float* __restrict__ hb2,
                                                   float* __restrict__ out, int G) {
    __shared__ float sW1[(NDIM + 1) * NDIM];
    __shared__ float sb1[NDIM];
    __shared__ float sW2[NDIM];
    for (int i = threadIdx.x; i < (NDIM + 1) * NDIM; i += 256) sW1[i] = hW1[i];
    if (threadIdx.x < NDIM) { sb1[threadIdx.x] = hb1[threadIdx.x]; sW2[threadIdx.x] = hW2[threadIdx.x]; }
    __syncthreads();
    const int lane = threadIdx.x & 63;
    int gw = (blockIdx.x * blockDim.x + threadIdx.x) >> 6;
    int nw = (gridDim.x * blockDim.x) >> 6;
    for (int g = gw; g < G; g += nw) {
        float c = fmaxf(cnt[g], 1.0f);
        float p = pooled[(size_t)g * NDIM + lane] / c;
        float t = t_cond[g];
        float o1 = fmaf(t, sW1[NDIM * NDIM + lane], sb1[lane]);
#pragma unroll 8
        for (int k = 0; k < NDIM; ++k) o1 = fmaf(__shfl(p, k), sW1[k * NDIM + lane], o1);
        o1 = fmaxf(o1, 0.0f);
        float v = o1 * sW2[lane];
        for (int off = 32; off > 0; off >>= 1) v += __shfl_down(v, off);
        if (lane == 0) out[g] = v + hb2[0];
    }
}

// ---------------- launch ----------------

extern "C" void kernel_launch(void* const* d_in, const int* in_sizes, int n_in,
                              void* d_out, int out_size, void* d_ws, size_t ws_size,
                              hipStream_t stream) {
    const float* x_in      = (const float*)d_in[0];
    const int*   edge_index= (const int*)  d_in[1];
    const float* edge_attr = (const float*)d_in[2];
    const int*   batch     = (const int*)  d_in[3];
    const float* t_cond    = (const float*)d_in[4];
    const float* lin_e     = (const float*)d_in[5];
    const float* W1        = (const float*)d_in[6];
    const float* b1        = (const float*)d_in[7];
    const float* W2        = (const float*)d_in[8];
    const float* b2        = (const float*)d_in[9];
    const float* eps       = (const float*)d_in[10];
    const float* hW1       = (const float*)d_in[11];
    const float* hb1       = (const float*)d_in[12];
    const float* hW2       = (const float*)d_in[13];
    const float* hb2       = (const float*)d_in[14];
    float* out = (float*)d_out;

    const int N = in_sizes[3];
    const int E = in_sizes[1] / 2;
    const int G = in_sizes[4];
    const int L = in_sizes[10];
    const int ntiles = (N + SCAN_TILE - 1) / SCAN_TILE;

    char* p = (char*)d_ws;
    auto alloc = [&](size_t bytes) { char* r = p; p += (bytes + 255) & ~(size_t)255; return r; };
    int*   rowptr = (int*)  alloc((size_t)(N + 1) * 4);
    int*   fillc  = (int*)  alloc((size_t)N * 4);
    int*   srcs   = (int*)  alloc((size_t)E * 4);
    int*   eids   = (int*)  alloc((size_t)E * 4);
    int*   tsum   = (int*)  alloc((size_t)ntiles * 4);
    float* bufA   = (float*)alloc((size_t)N * NDIM * 4);
    float* bufB   = (float*)alloc((size_t)N * NDIM * 4);
    float* pooled = (float*)alloc((size_t)G * NDIM * 4);
    float* cnt    = (float*)alloc((size_t)G * 4);

    // --- CSR build (per launch; ws is re-poisoned every call) ---
    hipMemsetAsync(fillc, 0, (size_t)N * 4, stream);
    hist_kernel<<<(E + 255) / 256, 256, 0, stream>>>(edge_index, fillc, E);
    scan_tile_kernel<<<ntiles, SCAN_BS, 0, stream>>>(fillc, rowptr, tsum, N);
    scan_sums_kernel<<<1, 64, 0, stream>>>(tsum, ntiles);
    scan_add_kernel<<<(N + 255) / 256, 256, 0, stream>>>(rowptr, tsum, fillc, N, E);
    fill_kernel<<<(E + 255) / 256, 256, 0, stream>>>(edge_index, fillc, srcs, eids, E);

    // --- 4 fused GINEConv layers (ping-pong x buffers) ---
    const int layer_blocks = 1024;
    const float* cur = x_in;
    float* nxt = bufA;
    for (int l = 0; l < L; ++l) {
        layer_kernel<<<layer_blocks, 256, 0, stream>>>(cur, nxt, rowptr, srcs, eids,
                                                       edge_attr, lin_e, W1, b1, W2, b2, eps, l, N);
        cur = nxt;
        nxt = (nxt == bufA) ? bufB : bufA;
    }

    // --- global mean pool ---
    hipMemsetAsync(pooled, 0, (size_t)G * NDIM * 4, stream);
    hipMemsetAsync(cnt, 0, (size_t)G * 4, stream);
    pool_kernel<<<512, 256, 0, stream>>>(cur, batch, pooled, cnt, N);

    // --- head ---
    head_kernel<<<(G + 3) / 4, 256, 0, stream>>>(pooled, cnt, t_cond, hW1, hb1, hW2, hb2, out, G);
}

// Round 2
// 1232.654 us; speedup vs baseline: 1.1560x; 1.1560x over previous
//
#include <hip/hip_runtime.h>

#define NDIM 64
#define EDIM 16
#define SCAN_BS 256
#define SCAN_TILE 2048   // SCAN_BS * 8

// ---------------- CSR build ----------------

__global__ __launch_bounds__(256) void hist_kernel(const int* __restrict__ edge_index,
                                                   int* __restrict__ deg, int E) {
    int e = blockIdx.x * blockDim.x + threadIdx.x;
    if (e < E) atomicAdd(&deg[edge_index[E + e]], 1);   // dst row
}

__global__ __launch_bounds__(SCAN_BS) void scan_tile_kernel(const int* __restrict__ deg,
                                                            int* __restrict__ excl,
                                                            int* __restrict__ tsum, int n) {
    __shared__ int sdata[SCAN_BS];
    int base = blockIdx.x * SCAN_TILE + threadIdx.x * 8;
    int v[8]; int s = 0;
#pragma unroll
    for (int j = 0; j < 8; ++j) { int idx = base + j; int val = (idx < n) ? deg[idx] : 0; v[j] = val; s += val; }
    sdata[threadIdx.x] = s;
    __syncthreads();
    for (int off = 1; off < SCAN_BS; off <<= 1) {
        int t = (threadIdx.x >= (unsigned)off) ? sdata[threadIdx.x - off] : 0;
        __syncthreads();
        sdata[threadIdx.x] += t;
        __syncthreads();
    }
    int incl = sdata[threadIdx.x];
    if (threadIdx.x == SCAN_BS - 1) tsum[blockIdx.x] = incl;
    int run = incl - s;  // exclusive prefix for this thread's chunk
#pragma unroll
    for (int j = 0; j < 8; ++j) { int idx = base + j; if (idx < n) excl[idx] = run; run += v[j]; }
}

__global__ void scan_sums_kernel(int* tsum, int ntiles) {
    if (threadIdx.x == 0 && blockIdx.x == 0) {
        int run = 0;
        for (int i = 0; i < ntiles; ++i) { int t = tsum[i]; tsum[i] = run; run += t; }
    }
}

__global__ __launch_bounds__(256) void scan_add_kernel(int* __restrict__ rowptr,
                                                       const int* __restrict__ tsum,
                                                       int* __restrict__ fillc, int n, int E) {
    int i = blockIdx.x * blockDim.x + threadIdx.x;
    if (i < n) {
        int v = rowptr[i] + tsum[i / SCAN_TILE];
        rowptr[i] = v;
        fillc[i] = v;
    }
    if (i == 0) rowptr[n] = E;
}

// fill + permute edge_attr into CSR order (kills eids indirection in the hot loop,
// makes attr reads sequential). Reads coalesced (thread e -> row e), writes random 64B.
__global__ __launch_bounds__(256) void fill2_kernel(const int* __restrict__ edge_index,
                                                    int* __restrict__ fillc,
                                                    int* __restrict__ srcs,
                                                    float4* __restrict__ gea,
                                                    const float4* __restrict__ ea, int E) {
    int e = blockIdx.x * blockDim.x + threadIdx.x;
    if (e < E) {
        int d = edge_index[E + e];
        int pos = atomicAdd(&fillc[d], 1);
        srcs[pos] = edge_index[e];
        float4 r0 = ea[(size_t)e*4+0], r1 = ea[(size_t)e*4+1],
               r2 = ea[(size_t)e*4+2], r3 = ea[(size_t)e*4+3];
        gea[(size_t)pos*4+0] = r0; gea[(size_t)pos*4+1] = r1;
        gea[(size_t)pos*4+2] = r2; gea[(size_t)pos*4+3] = r3;
    }
}

// fallback fill (no permuted ea) for small ws
__global__ __launch_bounds__(256) void fill_kernel(const int* __restrict__ edge_index,
                                                   int* __restrict__ fillc,
                                                   int* __restrict__ srcs,
                                                   int* __restrict__ eids, int E) {
    int e = blockIdx.x * blockDim.x + threadIdx.x;
    if (e < E) {
        int d = edge_index[E + e];
        int pos = atomicAdd(&fillc[d], 1);
        srcs[pos] = edge_index[e];
        eids[pos] = e;
    }
}

// ---------------- fused GINEConv layer (v2) ----------------
// One wave per node; lane = channel. srcs preloaded per-lane + shfl broadcast;
// edge loop unrolled x4 with all loads hoisted (ILP vs latency); permuted ea
// gives sequential attr reads. lin_e column + biases live in VGPRs; LDS = W1+W2 (32KB).

#define EDGE_FMA16(m, A0, A1, A2, A3)                                   \
    m = fmaf(A0.x, le[ 0], m); m = fmaf(A0.y, le[ 1], m);               \
    m = fmaf(A0.z, le[ 2], m); m = fmaf(A0.w, le[ 3], m);               \
    m = fmaf(A1.x, le[ 4], m); m = fmaf(A1.y, le[ 5], m);               \
    m = fmaf(A1.z, le[ 6], m); m = fmaf(A1.w, le[ 7], m);               \
    m = fmaf(A2.x, le[ 8], m); m = fmaf(A2.y, le[ 9], m);               \
    m = fmaf(A2.z, le[10], m); m = fmaf(A2.w, le[11], m);               \
    m = fmaf(A3.x, le[12], m); m = fmaf(A3.y, le[13], m);               \
    m = fmaf(A3.z, le[14], m); m = fmaf(A3.w, le[15], m);

__global__ __launch_bounds__(256, 4) void layer2_kernel(
    const float* __restrict__ xin, float* __restrict__ xout,
    const int* __restrict__ rowptr, const int* __restrict__ srcs,
    const float* __restrict__ gea,
    const float* __restrict__ lin_e, const float* __restrict__ W1, const float* __restrict__ b1,
    const float* __restrict__ W2, const float* __restrict__ b2, const float* __restrict__ eps,
    int layer, int n_nodes)
{
    __shared__ float s_W1[NDIM * NDIM];
    __shared__ float s_W2[NDIM * NDIM];
    const float* w1 = W1 + (size_t)layer * NDIM * NDIM;
    const float* w2 = W2 + (size_t)layer * NDIM * NDIM;
    for (int i = threadIdx.x; i < NDIM * NDIM; i += 256) { s_W1[i] = w1[i]; s_W2[i] = w2[i]; }
    const int lane = threadIdx.x & 63;
    float le[16];
    const float* lep = lin_e + (size_t)layer * EDIM * NDIM;
#pragma unroll
    for (int j = 0; j < EDIM; ++j) le[j] = lep[j * NDIM + lane];
    const float bb1 = b1[layer * NDIM + lane];
    const float bb2 = b2[layer * NDIM + lane];
    const float eps1 = 1.0f + eps[layer];
    __syncthreads();

    int gw = (blockIdx.x * blockDim.x + threadIdx.x) >> 6;
    int nw = (gridDim.x * blockDim.x) >> 6;
    for (int node = gw; node < n_nodes; node += nw) {
        int p0 = rowptr[node], p1 = rowptr[node + 1];
        float aggr = 0.0f;
        for (int base = p0; base < p1; base += 64) {
            int cnt = min(64, p1 - base);
            int s_l = (lane < cnt) ? srcs[base + lane] : 0;
            int p = 0;
            for (; p + 4 <= cnt; p += 4) {
                int s0 = __shfl(s_l, p), s1 = __shfl(s_l, p + 1),
                    s2 = __shfl(s_l, p + 2), s3 = __shfl(s_l, p + 3);
                float xs0 = xin[(size_t)s0 * NDIM + lane];
                float xs1 = xin[(size_t)s1 * NDIM + lane];
                float xs2 = xin[(size_t)s2 * NDIM + lane];
                float xs3 = xin[(size_t)s3 * NDIM + lane];
                const float4* ea = (const float4*)(gea + (size_t)(base + p) * EDIM);
                float4 a0 = ea[ 0], a1 = ea[ 1], a2 = ea[ 2], a3 = ea[ 3];
                float4 e0 = ea[ 4], e1 = ea[ 5], e2 = ea[ 6], e3 = ea[ 7];
                float4 c0 = ea[ 8], c1 = ea[ 9], c2 = ea[10], c3 = ea[11];
                float4 d0 = ea[12], d1 = ea[13], d2 = ea[14], d3 = ea[15];
                float m0 = xs0, m1 = xs1, m2 = xs2, m3 = xs3;
                EDGE_FMA16(m0, a0, a1, a2, a3)
                EDGE_FMA16(m1, e0, e1, e2, e3)
                EDGE_FMA16(m2, c0, c1, c2, c3)
                EDGE_FMA16(m3, d0, d1, d2, d3)
                aggr += fmaxf(m0, 0.0f) + fmaxf(m1, 0.0f) + fmaxf(m2, 0.0f) + fmaxf(m3, 0.0f);
            }
            for (; p < cnt; ++p) {
                int s0 = __shfl(s_l, p);
                float xs0 = xin[(size_t)s0 * NDIM + lane];
                const float4* ea = (const float4*)(gea + (size_t)(base + p) * EDIM);
                float4 a0 = ea[0], a1 = ea[1], a2 = ea[2], a3 = ea[3];
                float m0 = xs0;
                EDGE_FMA16(m0, a0, a1, a2, a3)
                aggr += fmaxf(m0, 0.0f);
            }
        }
        float h = fmaf(eps1, xin[(size_t)node * NDIM + lane], aggr);
        float o1 = bb1;
#pragma unroll 8
        for (int k = 0; k < NDIM; ++k) o1 = fmaf(__shfl(h, k), s_W1[k * NDIM + lane], o1);
        o1 = fmaxf(o1, 0.0f);
        float o2 = bb2;
#pragma unroll 8
        for (int k = 0; k < NDIM; ++k) o2 = fmaf(__shfl(o1, k), s_W2[k * NDIM + lane], o2);
        xout[(size_t)node * NDIM + lane] = fmaxf(o2, 0.0f);
    }
}

// fallback layer (round-1 version, eids-based) for small ws
__global__ __launch_bounds__(256) void layer_kernel(
    const float* __restrict__ xin, float* __restrict__ xout,
    const int* __restrict__ rowptr, const int* __restrict__ srcs, const int* __restrict__ eids,
    const float* __restrict__ edge_attr,
    const float* __restrict__ lin_e, const float* __restrict__ W1, const float* __restrict__ b1,
    const float* __restrict__ W2, const float* __restrict__ b2, const float* __restrict__ eps,
    int layer, int n_nodes)
{
    __shared__ float s_W1[NDIM * NDIM];
    __shared__ float s_W2[NDIM * NDIM];
    const float* w1 = W1 + (size_t)layer * NDIM * NDIM;
    const float* w2 = W2 + (size_t)layer * NDIM * NDIM;
    for (int i = threadIdx.x; i < NDIM * NDIM; i += 256) { s_W1[i] = w1[i]; s_W2[i] = w2[i]; }
    const int lane = threadIdx.x & 63;
    float le[16];
    const float* lep = lin_e + (size_t)layer * EDIM * NDIM;
#pragma unroll
    for (int j = 0; j < EDIM; ++j) le[j] = lep[j * NDIM + lane];
    const float bb1 = b1[layer * NDIM + lane];
    const float bb2 = b2[layer * NDIM + lane];
    const float eps1 = 1.0f + eps[layer];
    __syncthreads();
    int gw = (blockIdx.x * blockDim.x + threadIdx.x) >> 6;
    int nw = (gridDim.x * blockDim.x) >> 6;
    for (int node = gw; node < n_nodes; node += nw) {
        int p0 = rowptr[node], p1 = rowptr[node + 1];
        float aggr = 0.0f;
        for (int p = p0; p < p1; ++p) {
            int s = srcs[p];
            int e = eids[p];
            float xs = xin[(size_t)s * NDIM + lane];
            const float4* ea = (const float4*)(edge_attr + (size_t)e * EDIM);
            float4 a0 = ea[0], a1 = ea[1], a2 = ea[2], a3 = ea[3];
            float m0 = xs;
            EDGE_FMA16(m0, a0, a1, a2, a3)
            aggr += fmaxf(m0, 0.0f);
        }
        float h = fmaf(eps1, xin[(size_t)node * NDIM + lane], aggr);
        float o1 = bb1;
#pragma unroll 8
        for (int k = 0; k < NDIM; ++k) o1 = fmaf(__shfl(h, k), s_W1[k * NDIM + lane], o1);
        o1 = fmaxf(o1, 0.0f);
        float o2 = bb2;
#pragma unroll 8
        for (int k = 0; k < NDIM; ++k) o2 = fmaf(__shfl(o1, k), s_W2[k * NDIM + lane], o2);
        xout[(size_t)node * NDIM + lane] = fmaxf(o2, 0.0f);
    }
}

// ---------------- pooling + head ----------------

__global__ __launch_bounds__(256) void pool_kernel(const float* __restrict__ x,
                                                   const int* __restrict__ batch,
                                                   float* __restrict__ pooled,
                                                   float* __restrict__ cnt, int n_nodes) {
    const int lane = threadIdx.x & 63;
    int gw = (blockIdx.x * blockDim.x + threadIdx.x) >> 6;
    int nw = (gridDim.x * blockDim.x) >> 6;
    for (int node = gw; node < n_nodes; node += nw) {
        int g = batch[node];
        atomicAdd(&pooled[(size_t)g * NDIM + lane], x[(size_t)node * NDIM + lane]);
        if (lane == 0) atomicAdd(&cnt[g], 1.0f);
    }
}

__global__ __launch_bounds__(256) void head_kernel(const float* __restrict__ pooled,
                                                   const float* __restrict__ cnt,
                                                   const float* __restrict__ t_cond,
                                                   const float* __restrict__ hW1,
                                                   const float* __restrict__ hb1,
                                                   const float* __restrict__ hW2,
                                                   const float* __restrict__ hb2,
                                                   float* __restrict__ out, int G) {
    __shared__ float sW1[(NDIM + 1) * NDIM];
    __shared__ float sb1[NDIM];
    __shared__ float sW2[NDIM];
    for (int i = threadIdx.x; i < (NDIM + 1) * NDIM; i += 256) sW1[i] = hW1[i];
    if (threadIdx.x < NDIM) { sb1[threadIdx.x] = hb1[threadIdx.x]; sW2[threadIdx.x] = hW2[threadIdx.x]; }
    __syncthreads();
    const int lane = threadIdx.x & 63;
    int gw = (blockIdx.x * blockDim.x + threadIdx.x) >> 6;
    int nw = (gridDim.x * blockDim.x) >> 6;
    for (int g = gw; g < G; g += nw) {
        float c = fmaxf(cnt[g], 1.0f);
        float p = pooled[(size_t)g * NDIM + lane] / c;
        float t = t_cond[g];
        float o1 = fmaf(t, sW1[NDIM * NDIM + lane], sb1[lane]);
#pragma unroll 8
        for (int k = 0; k < NDIM; ++k) o1 = fmaf(__shfl(p, k), sW1[k * NDIM + lane], o1);
        o1 = fmaxf(o1, 0.0f);
        float v = o1 * sW2[lane];
        for (int off = 32; off > 0; off >>= 1) v += __shfl_down(v, off);
        if (lane == 0) out[g] = v + hb2[0];
    }
}

// ---------------- launch ----------------

extern "C" void kernel_launch(void* const* d_in, const int* in_sizes, int n_in,
                              void* d_out, int out_size, void* d_ws, size_t ws_size,
                              hipStream_t stream) {
    const float* x_in      = (const float*)d_in[0];
    const int*   edge_index= (const int*)  d_in[1];
    const float* edge_attr = (const float*)d_in[2];
    const int*   batch     = (const int*)  d_in[3];
    const float* t_cond    = (const float*)d_in[4];
    const float* lin_e     = (const float*)d_in[5];
    const float* W1        = (const float*)d_in[6];
    const float* b1        = (const float*)d_in[7];
    const float* W2        = (const float*)d_in[8];
    const float* b2        = (const float*)d_in[9];
    const float* eps       = (const float*)d_in[10];
    const float* hW1       = (const float*)d_in[11];
    const float* hb1       = (const float*)d_in[12];
    const float* hW2       = (const float*)d_in[13];
    const float* hb2       = (const float*)d_in[14];
    float* out = (float*)d_out;

    const int N = in_sizes[3];
    const int E = in_sizes[1] / 2;
    const int G = in_sizes[4];
    const int L = in_sizes[10];
    const int ntiles = (N + SCAN_TILE - 1) / SCAN_TILE;

    char* p = (char*)d_ws;
    auto alloc = [&](size_t bytes) { char* r = p; p += (bytes + 255) & ~(size_t)255; return r; };
    int*   rowptr = (int*)  alloc((size_t)(N + 1) * 4);
    int*   fillc  = (int*)  alloc((size_t)N * 4);
    int*   srcs   = (int*)  alloc((size_t)E * 4);
    int*   tsum   = (int*)  alloc((size_t)ntiles * 4);
    float* bufA   = (float*)alloc((size_t)N * NDIM * 4);
    float* bufB   = (float*)alloc((size_t)N * NDIM * 4);
    float* pooled = (float*)alloc((size_t)G * NDIM * 4);
    float* cnt    = (float*)alloc((size_t)G * 4);
    // big buffer last so the fallback path needs none of it
    size_t base_used = (size_t)(p - (char*)d_ws);
    float* gea    = (float*)alloc((size_t)E * EDIM * 4);
    bool use_gea = (base_used + (size_t)E * EDIM * 4) <= ws_size;
    int* eids = use_gea ? nullptr : (int*)((char*)d_ws + base_used); // reuse gea slot head (E*4 fits)

    // --- CSR build ---
    hipMemsetAsync(fillc, 0, (size_t)N * 4, stream);
    hist_kernel<<<(E + 255) / 256, 256, 0, stream>>>(edge_index, fillc, E);
    scan_tile_kernel<<<ntiles, SCAN_BS, 0, stream>>>(fillc, rowptr, tsum, N);
    scan_sums_kernel<<<1, 64, 0, stream>>>(tsum, ntiles);
    scan_add_kernel<<<(N + 255) / 256, 256, 0, stream>>>(rowptr, tsum, fillc, N, E);
    if (use_gea) {
        fill2_kernel<<<(E + 255) / 256, 256, 0, stream>>>(edge_index, fillc, srcs,
                                                          (float4*)gea, (const float4*)edge_attr, E);
    } else {
        fill_kernel<<<(E + 255) / 256, 256, 0, stream>>>(edge_index, fillc, srcs, eids, E);
    }

    // --- 4 fused GINEConv layers (ping-pong x buffers) ---
    const int layer_blocks = 1024;
    const float* cur = x_in;
    float* nxt = bufA;
    for (int l = 0; l < L; ++l) {
        if (use_gea) {
            layer2_kernel<<<layer_blocks, 256, 0, stream>>>(cur, nxt, rowptr, srcs, gea,
                                                            lin_e, W1, b1, W2, b2, eps, l, N);
        } else {
            layer_kernel<<<layer_blocks, 256, 0, stream>>>(cur, nxt, rowptr, srcs, eids,
                                                           edge_attr, lin_e, W1, b1, W2, b2, eps, l, N);
        }
        cur = nxt;
        nxt = (nxt == bufA) ? bufB : bufA;
    }

    // --- global mean pool ---
    hipMemsetAsync(pooled, 0, (size_t)G * NDIM * 4, stream);
    hipMemsetAsync(cnt, 0, (size_t)G * 4, stream);
    pool_kernel<<<512, 256, 0, stream>>>(cur, batch, pooled, cnt, N);

    // --- head ---
    head_kernel<<<(G + 3) / 4, 256, 0, stream>>>(pooled, cnt, t_cond, hW1, hb1, hW2, hb2, out, G);
}